// Round 14
// baseline (252.306 us; speedup 1.0000x reference)
//
#include <hip/hip_runtime.h>

#define HD 16
#define DHEAD 64
#define DMODEL 1024
#define BB 2
#define SS 2048
#define MTOT (BB*SS)   // 4096
#define LOG2E 1.44269504f

typedef float f32x4 __attribute__((ext_vector_type(4)));
typedef float f32x16 __attribute__((ext_vector_type(16)));
typedef __bf16 bf16x8 __attribute__((ext_vector_type(8)));
typedef unsigned short u16x8 __attribute__((ext_vector_type(8)));
typedef unsigned int u32x2 __attribute__((ext_vector_type(2)));
typedef unsigned int u32x4 __attribute__((ext_vector_type(4)));

__device__ __forceinline__ unsigned short f2bf(float f) {
    unsigned int u = __builtin_bit_cast(unsigned int, f);
    unsigned int r = (u + 0x7fffu + ((u >> 16) & 1u)) >> 16;   // RNE
    return (unsigned short)r;
}

__device__ __forceinline__ float bf2f(unsigned short u) {
    return __builtin_bit_cast(float, ((unsigned int)u) << 16);
}

__device__ __forceinline__ bf16x8 ld8(const unsigned short* p) {
    u16x8 v = *reinterpret_cast<const u16x8*>(p);
    return __builtin_bit_cast(bf16x8, v);
}

__device__ __forceinline__ void gload_lds16b(const char* g, char* l) {
    __builtin_amdgcn_global_load_lds(
        (const __attribute__((address_space(1))) void*)g,
        (__attribute__((address_space(3))) void*)l, 16, 0, 0);
}

__device__ __forceinline__ unsigned cvt_pk_bf16(float lo, float hi) {
    unsigned r;
    asm("v_cvt_pk_bf16_f32 %0, %1, %2" : "=v"(r) : "v"(lo), "v"(hi));
    return r;
}

// ---------------- fp32 -> bf16 converts (one launch: 4 weights + x) ----------------
__global__ __launch_bounds__(256) void cvt_all(
    const float* __restrict__ x,
    const float* __restrict__ w0, const float* __restrict__ w1,
    const float* __restrict__ w2, const float* __restrict__ w3,
    unsigned short* __restrict__ xb,
    unsigned short* __restrict__ o0, unsigned short* __restrict__ o1,
    unsigned short* __restrict__ o2, unsigned short* __restrict__ o3) {
    int y = blockIdx.y;
    const float* in;
    unsigned short* out;
    int idx;
    if (y < 4) {
        in  = (y == 0) ? w0 : (y == 1) ? w1 : (y == 2) ? w2 : w3;
        out = (y == 0) ? o0 : (y == 1) ? o1 : (y == 2) ? o2 : o3;
        idx = blockIdx.x * 256 + threadIdx.x;
    } else {
        in  = x;
        out = xb;
        idx = ((y - 4) * 1024 + blockIdx.x) * 256 + threadIdx.x;
    }
    float4 v = reinterpret_cast<const float4*>(in)[idx];
    ushort4 o;
    o.x = f2bf(v.x); o.y = f2bf(v.y); o.z = f2bf(v.z); o.w = f2bf(v.w);
    reinterpret_cast<ushort4*>(out)[idx] = o;
}

// ---------------- QKV projection: 128x128 tile, BK=64, 32x32 MFMA, dbuf+counted vmcnt ----------------
__global__ __launch_bounds__(256, 2) void gemm_qkv(
    const unsigned short* __restrict__ xb,
    const unsigned short* __restrict__ Wqb, const unsigned short* __restrict__ Wkb,
    const unsigned short* __restrict__ Wvb,
    const float* __restrict__ bq, const float* __restrict__ bk, const float* __restrict__ bv,
    unsigned short* __restrict__ Qo, unsigned short* __restrict__ Ko, unsigned short* __restrict__ VTo) {
    __shared__ unsigned short Als[2][8192];   // [128 m][64 k] bf16, swizzled, 16KB/buf
    __shared__ unsigned short Bls[2][8192];   // [128 n][64 k]
    int L = blockIdx.x;
    int wg = (L & 7) * 96 + (L >> 3);         // bijective XCD-chunked remap (768 = 8*96)
    int z = wg >> 8, rem = wg & 255;
    int n0 = (rem & 7) * 128, m0 = (rem >> 3) * 128;
    const unsigned short* Bm = (z == 0) ? Wqb : (z == 1) ? Wkb : Wvb;
    const float* bias = (z == 0) ? bq : (z == 1) ? bk : bv;

    int t = threadIdx.x, wv = t >> 6, lane = t & 63;
    int q5 = lane & 31, hi = lane >> 5;
    int wm = wv >> 1, wn = wv & 1;
    const char* Ac = (const char*)xb;
    const char* Bc = (const char*)Bm;

    auto stage = [&](int bf, int k0) {
#pragma unroll
        for (int i = 0; i < 4; ++i) {
            int c = t + 256 * i;
            int kr = c >> 3, kc = ((c & 7) << 4) ^ ((kr & 7) << 4);
            gload_lds16b(Ac + ((size_t)(m0 + kr) * DMODEL + k0) * 2 + kc, (char*)&Als[bf][0] + c * 16);
        }
#pragma unroll
        for (int i = 0; i < 4; ++i) {
            int c = t + 256 * i;
            int kr = c >> 3, kc = ((c & 7) << 4) ^ ((kr & 7) << 4);
            gload_lds16b(Bc + ((size_t)(n0 + kr) * DMODEL + k0) * 2 + kc, (char*)&Bls[bf][0] + c * 16);
        }
    };

    f32x16 acc[2][2];
#pragma unroll
    for (int fm = 0; fm < 2; ++fm)
#pragma unroll
        for (int fn = 0; fn < 2; ++fn) acc[fm][fn] = (f32x16)0.f;

    stage(0, 0);
    int buf = 0;
    for (int k0 = 0; k0 < DMODEL; k0 += 64) {
        __builtin_amdgcn_s_barrier();
        if (k0 + 64 < DMODEL) {
            stage(buf ^ 1, k0 + 64);
            asm volatile("s_waitcnt vmcnt(8)" ::: "memory");
        } else {
            asm volatile("s_waitcnt vmcnt(0)" ::: "memory");
        }
        __builtin_amdgcn_sched_barrier(0);
        __builtin_amdgcn_s_barrier();
        __builtin_amdgcn_sched_barrier(0);

        const char* als = (const char*)&Als[buf][0];
        const char* bls = (const char*)&Bls[buf][0];
        __builtin_amdgcn_s_setprio(1);
#pragma unroll
        for (int ks = 0; ks < 4; ++ks) {
            int kb = ks * 32 + hi * 16;
            bf16x8 af[2], bfr[2];
#pragma unroll
            for (int fm = 0; fm < 2; ++fm) {
                int row = wm * 64 + fm * 32 + q5;
                af[fm] = *reinterpret_cast<const bf16x8*>(als + row * 128 + (kb ^ ((row & 7) << 4)));
            }
#pragma unroll
            for (int fn = 0; fn < 2; ++fn) {
                int row = wn * 64 + fn * 32 + q5;
                bfr[fn] = *reinterpret_cast<const bf16x8*>(bls + row * 128 + (kb ^ ((row & 7) << 4)));
            }
#pragma unroll
            for (int fm = 0; fm < 2; ++fm)
#pragma unroll
                for (int fn = 0; fn < 2; ++fn)
                    acc[fm][fn] = __builtin_amdgcn_mfma_f32_32x32x16_bf16(af[fm], bfr[fn], acc[fm][fn], 0, 0, 0);
        }
        __builtin_amdgcn_s_setprio(0);
        buf ^= 1;
    }

    float scale = (z == 0) ? (0.125f * LOG2E) : 1.0f;   // fold 1/sqrt(64)*log2(e) into Q
    int b = m0 >> 11;
#pragma unroll
    for (int fm = 0; fm < 2; ++fm) {
#pragma unroll
        for (int fn = 0; fn < 2; ++fn) {
            int col = n0 + wn * 64 + fn * 32 + q5;
            int h = col >> 6, dh = col & 63;
            float bi = bias[col];
            if (z == 2) {
#pragma unroll
                for (int rq = 0; rq < 4; ++rq) {
                    int s0 = ((m0 + wm * 64 + fm * 32 + 8 * rq + 4 * hi) & 2047);
                    ushort4 pk;
                    pk.x = f2bf(acc[fm][fn][4 * rq + 0] + bi);
                    pk.y = f2bf(acc[fm][fn][4 * rq + 1] + bi);
                    pk.z = f2bf(acc[fm][fn][4 * rq + 2] + bi);
                    pk.w = f2bf(acc[fm][fn][4 * rq + 3] + bi);
                    *reinterpret_cast<ushort4*>(&VTo[((size_t)((b * HD + h) * DHEAD + dh)) * SS + s0]) = pk;
                }
            } else {
                unsigned short* o = (z == 0) ? Qo : Ko;   // [bh][s][dh]
#pragma unroll
                for (int r = 0; r < 16; ++r) {
                    int s = (m0 + wm * 64 + fm * 32 + (r & 3) + 8 * (r >> 2) + 4 * hi) & 2047;
                    o[((size_t)((b * HD + h) * SS + s)) * DHEAD + dh] = f2bf((acc[fm][fn][r] + bi) * scale);
                }
            }
        }
    }
}

// ---------------- flash attention: 4 waves x 32 q, 32 phases of 64 t, 4-buffer ring (R13) ----------------
__global__ __launch_bounds__(256, 2) void attn_kernel(
    const unsigned short* __restrict__ Qb, const unsigned short* __restrict__ Kb,
    const unsigned short* __restrict__ VTb, unsigned short* __restrict__ ctxo) {
    __shared__ char smem[4][16384];   // ring buffers: [K 8KB | V 8KB] each
    int L = blockIdx.x + (int)gridDim.x * blockIdx.y;   // 0..511
    int wg = (L & 7) * 64 + (L >> 3);                   // bijective XCD-chunked remap
    int q0 = (wg & 15) * 128;
    int bh = wg >> 4;
    int t = threadIdx.x, wv = t >> 6, lane = t & 63;
    int q5 = lane & 31, hi = lane >> 5;
    const unsigned short* Qh  = Qb  + (size_t)bh * SS * DHEAD;
    const char* Khc  = (const char*)(Kb  + (size_t)bh * SS * DHEAD);
    const char* VThc = (const char*)(VTb + (size_t)bh * DHEAD * SS);
    int qr = q0 + wv * 32;

    bf16x8 qf[4];
#pragma unroll
    for (int m = 0; m < 4; ++m)
        qf[m] = ld8(&Qh[(size_t)(qr + q5) * DHEAD + m * 16 + hi * 8]);

    const __bf16 one_bf = (__bf16)1.0f;
    bf16x8 ones8 = {one_bf, one_bf, one_bf, one_bf, one_bf, one_bf, one_bf, one_bf};

    f32x16 oo[2];
    oo[0] = (f32x16)0.f; oo[1] = (f32x16)0.f;
    f32x16 ls = (f32x16)0.f;   // row-sums (o-layout) via mfma(P, ones)
    float mrun = 0.f;          // log2-units; defer-max THR=8

    auto stage = [&](int ph) {
        char* kb = smem[ph & 3];
        char* vb = kb + 8192;
        int t0 = ph * 64;
#pragma unroll
        for (int i = 0; i < 2; ++i) {
            int c = t + 256 * i;
            int kr = c >> 3, kc = ((c & 7) << 4) ^ ((kr & 7) << 4);
            gload_lds16b(Khc + (size_t)(t0 + kr) * 128 + kc, kb + c * 16);
        }
#pragma unroll
        for (int i = 0; i < 2; ++i) {
            int c = t + 256 * i;
            int vr = c >> 3, vc = ((c & 7) << 4) ^ ((vr & 7) << 4);
            gload_lds16b(VThc + ((size_t)vr * SS + t0) * 2 + vc, vb + c * 16);
        }
    };

    stage(0); stage(1); stage(2);   // 12 loads in flight

    for (int ph = 0; ph < 32; ++ph) {
        if (ph < 30)      asm volatile("s_waitcnt vmcnt(8)" ::: "memory");
        else if (ph == 30) asm volatile("s_waitcnt vmcnt(4)" ::: "memory");
        else              asm volatile("s_waitcnt vmcnt(0)" ::: "memory");
        __builtin_amdgcn_sched_barrier(0);
        __builtin_amdgcn_s_barrier();
        __builtin_amdgcn_sched_barrier(0);

        if (ph + 3 < 32) stage(ph + 3);

        const char* kls = smem[ph & 3];
        const char* vls = kls + 8192;

        f32x16 sc[2];
        __builtin_amdgcn_s_setprio(1);
#pragma unroll
        for (int tb = 0; tb < 2; ++tb) {
            int row = tb * 32 + q5;
            int rsw = (row & 7) << 4;
            f32x16 s = (f32x16)0.f;
#pragma unroll
            for (int m = 0; m < 4; ++m) {
                bf16x8 kf = *reinterpret_cast<const bf16x8*>(kls + row * 128 + ((m * 32 + hi * 16) ^ rsw));
                s = __builtin_amdgcn_mfma_f32_32x32x16_bf16(kf, qf[m], s, 0, 0, 0);
            }
            sc[tb] = s;
        }
        __builtin_amdgcn_s_setprio(0);

        float mx[16];
#pragma unroll
        for (int r = 0; r < 16; ++r) mx[r] = fmaxf(sc[0][r], sc[1][r]);
#pragma unroll
        for (int st = 8; st; st >>= 1)
#pragma unroll
            for (int r = 0; r < st; ++r) mx[r] = fmaxf(mx[r], mx[r + st]);
        float lm = mx[0];

        if (__any(lm > mrun + 8.f)) {
            u32x2 sw = __builtin_amdgcn_permlane32_swap(__builtin_bit_cast(unsigned, lm),
                                                        __builtin_bit_cast(unsigned, lm), false, false);
            float rowmax = fmaxf(__builtin_bit_cast(float, sw[0]), __builtin_bit_cast(float, sw[1]));
            float mn = fmaxf(mrun, rowmax);
            float al = exp2f(mrun - mn);
            mrun = mn;
#pragma unroll
            for (int r = 0; r < 16; ++r) {
                float alr = __shfl(al, (r & 3) + 8 * (r >> 2) + 4 * hi);
                oo[0][r] *= alr; oo[1][r] *= alr; ls[r] *= alr;
            }
        }

#pragma unroll
        for (int tb = 0; tb < 2; ++tb)
#pragma unroll
            for (int r = 0; r < 16; ++r)
                sc[tb][r] = exp2f(sc[tb][r] - mrun);

        u32x4 paw[4];
#pragma unroll
        for (int tb = 0; tb < 2; ++tb)
#pragma unroll
            for (int u2 = 0; u2 < 2; ++u2)
#pragma unroll
                for (int e = 0; e < 2; ++e) {
                    unsigned wd = cvt_pk_bf16(sc[tb][8 * u2 + 2 * e], sc[tb][8 * u2 + 2 * e + 1]);
                    unsigned ws = cvt_pk_bf16(sc[tb][8 * u2 + 4 + 2 * e], sc[tb][8 * u2 + 4 + 2 * e + 1]);
                    u32x2 rr = __builtin_amdgcn_permlane32_swap(wd, ws, false, false);
                    paw[tb * 2 + u2][e] = rr[0];
                    paw[tb * 2 + u2][2 + e] = rr[1];
                }

        __builtin_amdgcn_s_setprio(1);
#pragma unroll
        for (int dblk = 0; dblk < 2; ++dblk) {
            int row = dblk * 32 + q5;
            int rsw = (row & 7) << 4;
#pragma unroll
            for (int ks = 0; ks < 4; ++ks) {
                bf16x8 vf = *reinterpret_cast<const bf16x8*>(
                    vls + row * 128 + ((ks * 32 + hi * 16) ^ rsw));
                oo[dblk] = __builtin_amdgcn_mfma_f32_32x32x16_bf16(
                    __builtin_bit_cast(bf16x8, paw[ks]), vf, oo[dblk], 0, 0, 0);
            }
        }
#pragma unroll
        for (int ks = 0; ks < 4; ++ks)
            ls = __builtin_amdgcn_mfma_f32_32x32x16_bf16(
                __builtin_bit_cast(bf16x8, paw[ks]), ones8, ls, 0, 0, 0);
        __builtin_amdgcn_s_setprio(0);
    }

    int b = bh >> 4, h = bh & 15;
#pragma unroll
    for (int r = 0; r < 16; ++r) {
        float invr = 1.f / ls[r];
        int qrel = (r & 3) + 8 * (r >> 2) + 4 * hi;
        int s = qr + qrel;
        size_t base = ((size_t)(b * SS + s)) * DMODEL + h * DHEAD;
        ctxo[base + q5]      = f2bf(oo[0][r] * invr);
        ctxo[base + 32 + q5] = f2bf(oo[1][r] * invr);
    }
}

// ---------------- PROBE: barrier-free, LDS-free attention (K/V register-direct, L1-shared) ----------------
// Same math/geometry as attn_kernel. K double-buffered in regs (static kA/kB
// rotation), V issued early each phase; compiler inserts precise vmcnt waits.
__global__ __launch_bounds__(256) void attn_nobar(
    const unsigned short* __restrict__ Qb, const unsigned short* __restrict__ Kb,
    const unsigned short* __restrict__ VTb, unsigned short* __restrict__ ctxo) {
    int L = blockIdx.x + (int)gridDim.x * blockIdx.y;
    int wg = (L & 7) * 64 + (L >> 3);
    int q0 = (wg & 15) * 128;
    int bh = wg >> 4;
    int t = threadIdx.x, wv = t >> 6, lane = t & 63;
    int q5 = lane & 31, hi = lane >> 5;
    const unsigned short* Qh  = Qb  + (size_t)bh * SS * DHEAD;
    const unsigned short* Kh  = Kb  + (size_t)bh * SS * DHEAD;
    const unsigned short* VTh = VTb + (size_t)bh * DHEAD * SS;
    int qr = q0 + wv * 32;

    bf16x8 qf[4];
#pragma unroll
    for (int m = 0; m < 4; ++m)
        qf[m] = ld8(&Qh[(size_t)(qr + q5) * DHEAD + m * 16 + hi * 8]);

    const __bf16 one_bf = (__bf16)1.0f;
    bf16x8 ones8 = {one_bf, one_bf, one_bf, one_bf, one_bf, one_bf, one_bf, one_bf};

    f32x16 oo[2];
    oo[0] = (f32x16)0.f; oo[1] = (f32x16)0.f;
    f32x16 ls = (f32x16)0.f;
    float mrun = 0.f;

    bf16x8 kA[8], kB[8];
#pragma unroll
    for (int tb = 0; tb < 2; ++tb)
#pragma unroll
        for (int m = 0; m < 4; ++m)
            kA[tb * 4 + m] = ld8(&Kh[(size_t)(tb * 32 + q5) * DHEAD + m * 16 + hi * 8]);

    auto body = [&](int ph, bf16x8 (&kcur)[8], bf16x8 (&knext)[8]) {
        int t0 = ph * 64;
        // issue V(ph) early
        bf16x8 vf[8];
#pragma unroll
        for (int dblk = 0; dblk < 2; ++dblk)
#pragma unroll
            for (int ks = 0; ks < 4; ++ks)
                vf[dblk * 4 + ks] = ld8(&VTh[(size_t)(dblk * 32 + q5) * SS + t0 + ks * 16 + hi * 8]);
        // issue K(ph+1)
        if (ph + 1 < 32) {
#pragma unroll
            for (int tb = 0; tb < 2; ++tb)
#pragma unroll
                for (int m = 0; m < 4; ++m)
                    knext[tb * 4 + m] = ld8(&Kh[(size_t)(t0 + 64 + tb * 32 + q5) * DHEAD + m * 16 + hi * 8]);
        }

        f32x16 sc[2];
        __builtin_amdgcn_s_setprio(1);
#pragma unroll
        for (int tb = 0; tb < 2; ++tb) {
            f32x16 s = (f32x16)0.f;
#pragma unroll
            for (int m = 0; m < 4; ++m)
                s = __builtin_amdgcn_mfma_f32_32x32x16_bf16(kcur[tb * 4 + m], qf[m], s, 0, 0, 0);
            sc[tb] = s;
        }
        __builtin_amdgcn_s_setprio(0);

        float mx[16];
#pragma unroll
        for (int r = 0; r < 16; ++r) mx[r] = fmaxf(sc[0][r], sc[1][r]);
#pragma unroll
        for (int st = 8; st; st >>= 1)
#pragma unroll
            for (int r = 0; r < st; ++r) mx[r] = fmaxf(mx[r], mx[r + st]);
        float lm = mx[0];

        if (__any(lm > mrun + 8.f)) {
            u32x2 sw = __builtin_amdgcn_permlane32_swap(__builtin_bit_cast(unsigned, lm),
                                                        __builtin_bit_cast(unsigned, lm), false, false);
            float rowmax = fmaxf(__builtin_bit_cast(float, sw[0]), __builtin_bit_cast(float, sw[1]));
            float mn = fmaxf(mrun, rowmax);
            float al = exp2f(mrun - mn);
            mrun = mn;
#pragma unroll
            for (int r = 0; r < 16; ++r) {
                float alr = __shfl(al, (r & 3) + 8 * (r >> 2) + 4 * hi);
                oo[0][r] *= alr; oo[1][r] *= alr; ls[r] *= alr;
            }
        }

#pragma unroll
        for (int tb = 0; tb < 2; ++tb)
#pragma unroll
            for (int r = 0; r < 16; ++r)
                sc[tb][r] = exp2f(sc[tb][r] - mrun);

        u32x4 paw[4];
#pragma unroll
        for (int tb = 0; tb < 2; ++tb)
#pragma unroll
            for (int u2 = 0; u2 < 2; ++u2)
#pragma unroll
                for (int e = 0; e < 2; ++e) {
                    unsigned wd = cvt_pk_bf16(sc[tb][8 * u2 + 2 * e], sc[tb][8 * u2 + 2 * e + 1]);
                    unsigned ws = cvt_pk_bf16(sc[tb][8 * u2 + 4 + 2 * e], sc[tb][8 * u2 + 4 + 2 * e + 1]);
                    u32x2 rr = __builtin_amdgcn_permlane32_swap(wd, ws, false, false);
                    paw[tb * 2 + u2][e] = rr[0];
                    paw[tb * 2 + u2][2 + e] = rr[1];
                }

        __builtin_amdgcn_s_setprio(1);
#pragma unroll
        for (int dblk = 0; dblk < 2; ++dblk)
#pragma unroll
            for (int ks = 0; ks < 4; ++ks)
                oo[dblk] = __builtin_amdgcn_mfma_f32_32x32x16_bf16(
                    __builtin_bit_cast(bf16x8, paw[ks]), vf[dblk * 4 + ks], oo[dblk], 0, 0, 0);
#pragma unroll
        for (int ks = 0; ks < 4; ++ks)
            ls = __builtin_amdgcn_mfma_f32_32x32x16_bf16(
                __builtin_bit_cast(bf16x8, paw[ks]), ones8, ls, 0, 0, 0);
        __builtin_amdgcn_s_setprio(0);
    };

    for (int pp = 0; pp < 16; ++pp) {
        body(2 * pp,     kA, kB);
        body(2 * pp + 1, kB, kA);
    }

    int b = bh >> 4, h = bh & 15;
#pragma unroll
    for (int r = 0; r < 16; ++r) {
        float invr = 1.f / ls[r];
        int qrel = (r & 3) + 8 * (r >> 2) + 4 * hi;
        int s = qr + qrel;
        size_t base = ((size_t)(b * SS + s)) * DMODEL + h * DHEAD;
        ctxo[base + q5]      = f2bf(oo[0][r] * invr);
        ctxo[base + 32 + q5] = f2bf(oo[1][r] * invr);
    }
}

// ---------------- output projection -> BF16 proj (halves proj/LN bandwidth) ----------------
__global__ __launch_bounds__(256, 2) void gemm_proj(
    const unsigned short* __restrict__ ctxb, const unsigned short* __restrict__ Wdb,
    const float* __restrict__ bd, unsigned short* __restrict__ projb) {
    __shared__ unsigned short Als[2][8192];   // [128 m][64 k]
    __shared__ unsigned short Bls[2][4096];   // [64 n][64 k]
    int L = blockIdx.x;
    int wg = (L & 7) * 64 + (L >> 3);         // 512 = 8*64
    int n0 = (wg & 15) * 64, m0 = (wg >> 4) * 128;

    int t = threadIdx.x, wv = t >> 6, lane = t & 63;
    int q5 = lane & 31, hi = lane >> 5;
    int wm = wv >> 1, wn = wv & 1;
    const char* Ac = (const char*)ctxb;
    const char* Bc = (const char*)Wdb;

    auto stage = [&](int bf, int k0) {
#pragma unroll
        for (int i = 0; i < 4; ++i) {
            int c = t + 256 * i;
            int kr = c >> 3, kc = ((c & 7) << 4) ^ ((kr & 7) << 4);
            gload_lds16b(Ac + ((size_t)(m0 + kr) * DMODEL + k0) * 2 + kc, (char*)&Als[bf][0] + c * 16);
        }
#pragma unroll
        for (int i = 0; i < 2; ++i) {
            int c = t + 256 * i;
            int kr = c >> 3, kc = ((c & 7) << 4) ^ ((kr & 7) << 4);
            gload_lds16b(Bc + ((size_t)(n0 + kr) * DMODEL + k0) * 2 + kc, (char*)&Bls[bf][0] + c * 16);
        }
    };

    f32x16 acc[2];
    acc[0] = (f32x16)0.f; acc[1] = (f32x16)0.f;

    stage(0, 0);
    int buf = 0;
    for (int k0 = 0; k0 < DMODEL; k0 += 64) {
        __builtin_amdgcn_s_barrier();
        if (k0 + 64 < DMODEL) {
            stage(buf ^ 1, k0 + 64);
            asm volatile("s_waitcnt vmcnt(6)" ::: "memory");
        } else {
            asm volatile("s_waitcnt vmcnt(0)" ::: "memory");
        }
        __builtin_amdgcn_sched_barrier(0);
        __builtin_amdgcn_s_barrier();
        __builtin_amdgcn_sched_barrier(0);

        const char* als = (const char*)&Als[buf][0];
        const char* bls = (const char*)&Bls[buf][0];
        __builtin_amdgcn_s_setprio(1);
#pragma unroll
        for (int ks = 0; ks < 4; ++ks) {
            int kb = ks * 32 + hi * 16;
            bf16x8 af[2], bfr;
#pragma unroll
            for (int fm = 0; fm < 2; ++fm) {
                int row = wm * 64 + fm * 32 + q5;
                af[fm] = *reinterpret_cast<const bf16x8*>(als + row * 128 + (kb ^ ((row & 7) << 4)));
            }
            {
                int row = wn * 32 + q5;
                bfr = *reinterpret_cast<const bf16x8*>(bls + row * 128 + (kb ^ ((row & 7) << 4)));
            }
#pragma unroll
            for (int fm = 0; fm < 2; ++fm)
                acc[fm] = __builtin_amdgcn_mfma_f32_32x32x16_bf16(af[fm], bfr, acc[fm], 0, 0, 0);
        }
        __builtin_amdgcn_s_setprio(0);
        buf ^= 1;
    }

    int col = n0 + wn * 32 + q5;
    float bi = bd[col];
#pragma unroll
    for (int fm = 0; fm < 2; ++fm)
#pragma unroll
        for (int r = 0; r < 16; ++r) {
            int row = m0 + wm * 64 + fm * 32 + (r & 3) + 8 * (r >> 2) + 4 * hi;
            projb[(size_t)row * DMODEL + col] = f2bf(acc[fm][r] + bi);
        }
}

// ---------------- LayerNorm over D=1024 (bf16 input) ----------------
__global__ __launch_bounds__(256) void ln_kernel(const unsigned short* __restrict__ projb,
                                                 const float* __restrict__ g,
                                                 const float* __restrict__ bv,
                                                 float* __restrict__ out) {
    int row = blockIdx.x, t = threadIdx.x;
    ushort4 u = reinterpret_cast<const ushort4*>(projb + (size_t)row * DMODEL)[t];
    float4 v;
    v.x = bf2f(u.x); v.y = bf2f(u.y); v.z = bf2f(u.z); v.w = bf2f(u.w);
    float s  = v.x + v.y + v.z + v.w;
    float s2 = v.x * v.x + v.y * v.y + v.z * v.z + v.w * v.w;
#pragma unroll
    for (int m = 1; m < 64; m <<= 1) { s += __shfl_xor(s, m); s2 += __shfl_xor(s2, m); }
    __shared__ float red[8];
    int wv = t >> 6, lane = t & 63;
    if (lane == 0) { red[wv] = s; red[wv + 4] = s2; }
    __syncthreads();
    s  = red[0] + red[1] + red[2] + red[3];
    s2 = red[4] + red[5] + red[6] + red[7];
    float mu  = s * (1.f / 1024.f);
    float var = s2 * (1.f / 1024.f) - mu * mu;
    float inv = rsqrtf(var + 1e-12f);
    float4 gv = reinterpret_cast<const float4*>(g)[t];
    float4 bb = reinterpret_cast<const float4*>(bv)[t];
    float4 ov;
    ov.x = (v.x - mu) * inv * gv.x + bb.x;
    ov.y = (v.y - mu) * inv * gv.y + bb.y;
    ov.z = (v.z - mu) * inv * gv.z + bb.z;
    ov.w = (v.w - mu) * inv * gv.w + bb.w;
    reinterpret_cast<float4*>(out + (size_t)row * DMODEL)[t] = ov;
}

extern "C" void kernel_launch(void* const* d_in, const int* in_sizes, int n_in,
                              void* d_out, int out_size, void* d_ws, size_t ws_size,
                              hipStream_t stream) {
    const float* x   = (const float*)d_in[0];
    const float* Wq  = (const float*)d_in[1];
    const float* bq  = (const float*)d_in[2];
    const float* Wk  = (const float*)d_in[3];
    const float* bk  = (const float*)d_in[4];
    const float* Wv  = (const float*)d_in[5];
    const float* bv  = (const float*)d_in[6];
    const float* Wd  = (const float*)d_in[7];
    const float* bd  = (const float*)d_in[8];
    const float* lng = (const float*)d_in[9];
    const float* lnb = (const float*)d_in[10];

    char* ws = (char*)d_ws;
    unsigned short* xb    = (unsigned short*)(ws);                    // 8 MB
    unsigned short* Wqb   = (unsigned short*)(ws + (8u  << 20));      // 2 MB each
    unsigned short* Wkb   = (unsigned short*)(ws + (10u << 20));
    unsigned short* Wvb   = (unsigned short*)(ws + (12u << 20));
    unsigned short* Wdb   = (unsigned short*)(ws + (14u << 20));
    unsigned short* Qb    = (unsigned short*)(ws + (16u << 20));      // 8 MB
    unsigned short* Kb    = (unsigned short*)(ws + (24u << 20));      // 8 MB
    unsigned short* VTb   = (unsigned short*)(ws + (32u << 20));      // 8 MB
    unsigned short* ctxb  = (unsigned short*)(ws + (40u << 20));      // 8 MB
    unsigned short* projb = (unsigned short*)(ws + (16u << 20));      // 8 MB, aliases Qb (dead after attn)

    cvt_all<<<dim3(1024, 8), 256, 0, stream>>>(x, Wq, Wk, Wv, Wd, xb, Wqb, Wkb, Wvb, Wdb);
    gemm_qkv<<<768, 256, 0, stream>>>(xb, Wqb, Wkb, Wvb, bq, bk, bv, Qb, Kb, VTb);
    attn_kernel<<<dim3(16, 32), 256, 0, stream>>>(Qb, Kb, VTb, ctxb);
    gemm_proj<<<512, 256, 0, stream>>>(ctxb, Wdb, bd, projb);
    ln_kernel<<<4096, 256, 0, stream>>>(projb, lng, lnb, (float*)d_out);

    // probe: barrier-free attention timing (writes to dead ctxb; result unused)
    attn_nobar<<<dim3(16, 32), 256, 0, stream>>>(Qb, Kb, VTb, ctxb);
}

// Round 15
// 135.070 us; speedup vs baseline: 1.8680x; 1.8680x over previous
//
#include <hip/hip_runtime.h>

#define HD 16
#define DHEAD 64
#define DMODEL 1024
#define BB 2
#define SS 2048
#define MTOT (BB*SS)   // 4096
#define LOG2E 1.44269504f

typedef float f32x4 __attribute__((ext_vector_type(4)));
typedef float f32x16 __attribute__((ext_vector_type(16)));
typedef __bf16 bf16x8 __attribute__((ext_vector_type(8)));
typedef unsigned short u16x8 __attribute__((ext_vector_type(8)));
typedef unsigned int u32x2 __attribute__((ext_vector_type(2)));
typedef unsigned int u32x4 __attribute__((ext_vector_type(4)));

__device__ __forceinline__ unsigned short f2bf(float f) {
    unsigned int u = __builtin_bit_cast(unsigned int, f);
    unsigned int r = (u + 0x7fffu + ((u >> 16) & 1u)) >> 16;   // RNE
    return (unsigned short)r;
}

__device__ __forceinline__ float bf2f(unsigned short u) {
    return __builtin_bit_cast(float, ((unsigned int)u) << 16);
}

__device__ __forceinline__ bf16x8 ld8(const unsigned short* p) {
    u16x8 v = *reinterpret_cast<const u16x8*>(p);
    return __builtin_bit_cast(bf16x8, v);
}

__device__ __forceinline__ void gload_lds16b(const char* g, char* l) {
    __builtin_amdgcn_global_load_lds(
        (const __attribute__((address_space(1))) void*)g,
        (__attribute__((address_space(3))) void*)l, 16, 0, 0);
}

__device__ __forceinline__ unsigned cvt_pk_bf16(float lo, float hi) {
    unsigned r;
    asm("v_cvt_pk_bf16_f32 %0, %1, %2" : "=v"(r) : "v"(lo), "v"(hi));
    return r;
}

// ---------------- fp32 -> bf16 converts (one launch: 4 weights + x) ----------------
__global__ __launch_bounds__(256) void cvt_all(
    const float* __restrict__ x,
    const float* __restrict__ w0, const float* __restrict__ w1,
    const float* __restrict__ w2, const float* __restrict__ w3,
    unsigned short* __restrict__ xb,
    unsigned short* __restrict__ o0, unsigned short* __restrict__ o1,
    unsigned short* __restrict__ o2, unsigned short* __restrict__ o3) {
    int y = blockIdx.y;
    const float* in;
    unsigned short* out;
    int idx;
    if (y < 4) {
        in  = (y == 0) ? w0 : (y == 1) ? w1 : (y == 2) ? w2 : w3;
        out = (y == 0) ? o0 : (y == 1) ? o1 : (y == 2) ? o2 : o3;
        idx = blockIdx.x * 256 + threadIdx.x;
    } else {
        in  = x;
        out = xb;
        idx = ((y - 4) * 1024 + blockIdx.x) * 256 + threadIdx.x;
    }
    float4 v = reinterpret_cast<const float4*>(in)[idx];
    ushort4 o;
    o.x = f2bf(v.x); o.y = f2bf(v.y); o.z = f2bf(v.z); o.w = f2bf(v.w);
    reinterpret_cast<ushort4*>(out)[idx] = o;
}

// ---------------- QKV projection: 128x128 tile, BK=64, 32x32 MFMA, dbuf+counted vmcnt ----------------
__global__ __launch_bounds__(256, 2) void gemm_qkv(
    const unsigned short* __restrict__ xb,
    const unsigned short* __restrict__ Wqb, const unsigned short* __restrict__ Wkb,
    const unsigned short* __restrict__ Wvb,
    const float* __restrict__ bq, const float* __restrict__ bk, const float* __restrict__ bv,
    unsigned short* __restrict__ Qo, unsigned short* __restrict__ Ko, unsigned short* __restrict__ VTo) {
    __shared__ unsigned short Als[2][8192];   // [128 m][64 k] bf16, swizzled, 16KB/buf
    __shared__ unsigned short Bls[2][8192];   // [128 n][64 k]
    int L = blockIdx.x;
    int wg = (L & 7) * 96 + (L >> 3);         // bijective XCD-chunked remap (768 = 8*96)
    int z = wg >> 8, rem = wg & 255;
    int n0 = (rem & 7) * 128, m0 = (rem >> 3) * 128;
    const unsigned short* Bm = (z == 0) ? Wqb : (z == 1) ? Wkb : Wvb;
    const float* bias = (z == 0) ? bq : (z == 1) ? bk : bv;

    int t = threadIdx.x, wv = t >> 6, lane = t & 63;
    int q5 = lane & 31, hi = lane >> 5;
    int wm = wv >> 1, wn = wv & 1;
    const char* Ac = (const char*)xb;
    const char* Bc = (const char*)Bm;

    auto stage = [&](int bf, int k0) {
#pragma unroll
        for (int i = 0; i < 4; ++i) {
            int c = t + 256 * i;
            int kr = c >> 3, kc = ((c & 7) << 4) ^ ((kr & 7) << 4);
            gload_lds16b(Ac + ((size_t)(m0 + kr) * DMODEL + k0) * 2 + kc, (char*)&Als[bf][0] + c * 16);
        }
#pragma unroll
        for (int i = 0; i < 4; ++i) {
            int c = t + 256 * i;
            int kr = c >> 3, kc = ((c & 7) << 4) ^ ((kr & 7) << 4);
            gload_lds16b(Bc + ((size_t)(n0 + kr) * DMODEL + k0) * 2 + kc, (char*)&Bls[bf][0] + c * 16);
        }
    };

    f32x16 acc[2][2];
#pragma unroll
    for (int fm = 0; fm < 2; ++fm)
#pragma unroll
        for (int fn = 0; fn < 2; ++fn) acc[fm][fn] = (f32x16)0.f;

    stage(0, 0);
    int buf = 0;
    for (int k0 = 0; k0 < DMODEL; k0 += 64) {
        __builtin_amdgcn_s_barrier();
        if (k0 + 64 < DMODEL) {
            stage(buf ^ 1, k0 + 64);
            asm volatile("s_waitcnt vmcnt(8)" ::: "memory");
        } else {
            asm volatile("s_waitcnt vmcnt(0)" ::: "memory");
        }
        __builtin_amdgcn_sched_barrier(0);
        __builtin_amdgcn_s_barrier();
        __builtin_amdgcn_sched_barrier(0);

        const char* als = (const char*)&Als[buf][0];
        const char* bls = (const char*)&Bls[buf][0];
        __builtin_amdgcn_s_setprio(1);
#pragma unroll
        for (int ks = 0; ks < 4; ++ks) {
            int kb = ks * 32 + hi * 16;
            bf16x8 af[2], bfr[2];
#pragma unroll
            for (int fm = 0; fm < 2; ++fm) {
                int row = wm * 64 + fm * 32 + q5;
                af[fm] = *reinterpret_cast<const bf16x8*>(als + row * 128 + (kb ^ ((row & 7) << 4)));
            }
#pragma unroll
            for (int fn = 0; fn < 2; ++fn) {
                int row = wn * 64 + fn * 32 + q5;
                bfr[fn] = *reinterpret_cast<const bf16x8*>(bls + row * 128 + (kb ^ ((row & 7) << 4)));
            }
#pragma unroll
            for (int fm = 0; fm < 2; ++fm)
#pragma unroll
                for (int fn = 0; fn < 2; ++fn)
                    acc[fm][fn] = __builtin_amdgcn_mfma_f32_32x32x16_bf16(af[fm], bfr[fn], acc[fm][fn], 0, 0, 0);
        }
        __builtin_amdgcn_s_setprio(0);
        buf ^= 1;
    }

    float scale = (z == 0) ? (0.125f * LOG2E) : 1.0f;   // fold 1/sqrt(64)*log2(e) into Q
    int b = m0 >> 11;
#pragma unroll
    for (int fm = 0; fm < 2; ++fm) {
#pragma unroll
        for (int fn = 0; fn < 2; ++fn) {
            int col = n0 + wn * 64 + fn * 32 + q5;
            int h = col >> 6, dh = col & 63;
            float bi = bias[col];
            if (z == 2) {
#pragma unroll
                for (int rq = 0; rq < 4; ++rq) {
                    int s0 = ((m0 + wm * 64 + fm * 32 + 8 * rq + 4 * hi) & 2047);
                    ushort4 pk;
                    pk.x = f2bf(acc[fm][fn][4 * rq + 0] + bi);
                    pk.y = f2bf(acc[fm][fn][4 * rq + 1] + bi);
                    pk.z = f2bf(acc[fm][fn][4 * rq + 2] + bi);
                    pk.w = f2bf(acc[fm][fn][4 * rq + 3] + bi);
                    *reinterpret_cast<ushort4*>(&VTo[((size_t)((b * HD + h) * DHEAD + dh)) * SS + s0]) = pk;
                }
            } else {
                unsigned short* o = (z == 0) ? Qo : Ko;   // [bh][s][dh]
#pragma unroll
                for (int r = 0; r < 16; ++r) {
                    int s = (m0 + wm * 64 + fm * 32 + (r & 3) + 8 * (r >> 2) + 4 * hi) & 2047;
                    o[((size_t)((b * HD + h) * SS + s)) * DHEAD + dh] = f2bf((acc[fm][fn][r] + bi) * scale);
                }
            }
        }
    }
}

// ---------------- flash attention: ring pipeline + C-init(-mrun) + max3 tree ----------------
// sc = S - mrun comes straight out of the QK MFMA (C operand initialized to
// splat(-mrun); mrun is lane-scalar since all 32 elements belong to q=q5).
// Common path: p = exp2(sc) with no subtract. Guard lm > 8 (adjusted units).
__global__ __launch_bounds__(256, 2) void attn_kernel(
    const unsigned short* __restrict__ Qb, const unsigned short* __restrict__ Kb,
    const unsigned short* __restrict__ VTb, unsigned short* __restrict__ ctxo) {
    __shared__ char smem[4][16384];   // ring buffers: [K 8KB | V 8KB] each
    int L = blockIdx.x + (int)gridDim.x * blockIdx.y;   // 0..511
    int wg = (L & 7) * 64 + (L >> 3);                   // bijective XCD-chunked remap
    int q0 = (wg & 15) * 128;
    int bh = wg >> 4;
    int t = threadIdx.x, wv = t >> 6, lane = t & 63;
    int q5 = lane & 31, hi = lane >> 5;
    const unsigned short* Qh  = Qb  + (size_t)bh * SS * DHEAD;
    const char* Khc  = (const char*)(Kb  + (size_t)bh * SS * DHEAD);
    const char* VThc = (const char*)(VTb + (size_t)bh * DHEAD * SS);
    int qr = q0 + wv * 32;

    bf16x8 qf[4];
#pragma unroll
    for (int m = 0; m < 4; ++m)
        qf[m] = ld8(&Qh[(size_t)(qr + q5) * DHEAD + m * 16 + hi * 8]);

    const __bf16 one_bf = (__bf16)1.0f;
    bf16x8 ones8 = {one_bf, one_bf, one_bf, one_bf, one_bf, one_bf, one_bf, one_bf};

    f32x16 oo[2];
    oo[0] = (f32x16)0.f; oo[1] = (f32x16)0.f;
    f32x16 ls = (f32x16)0.f;   // row-sums (o-layout) via mfma(P, ones)
    float mrun = 0.f;          // log2-units, lane-scalar (q=q5); defer-max THR=8

    auto stage = [&](int ph) {
        char* kb = smem[ph & 3];
        char* vb = kb + 8192;
        int t0 = ph * 64;
#pragma unroll
        for (int i = 0; i < 2; ++i) {
            int c = t + 256 * i;
            int kr = c >> 3, kc = ((c & 7) << 4) ^ ((kr & 7) << 4);
            gload_lds16b(Khc + (size_t)(t0 + kr) * 128 + kc, kb + c * 16);
        }
#pragma unroll
        for (int i = 0; i < 2; ++i) {
            int c = t + 256 * i;
            int vr = c >> 3, vc = ((c & 7) << 4) ^ ((vr & 7) << 4);
            gload_lds16b(VThc + ((size_t)vr * SS + t0) * 2 + vc, vb + c * 16);
        }
    };

    stage(0); stage(1); stage(2);   // 12 loads in flight

    for (int ph = 0; ph < 32; ++ph) {
        if (ph < 30)       asm volatile("s_waitcnt vmcnt(8)" ::: "memory");
        else if (ph == 30) asm volatile("s_waitcnt vmcnt(4)" ::: "memory");
        else               asm volatile("s_waitcnt vmcnt(0)" ::: "memory");
        __builtin_amdgcn_sched_barrier(0);
        __builtin_amdgcn_s_barrier();
        __builtin_amdgcn_sched_barrier(0);

        if (ph + 3 < 32) stage(ph + 3);

        const char* kls = smem[ph & 3];
        const char* vls = kls + 8192;

        // QK^T with C initialized to -mrun: sc = S - mrun directly
        f32x16 sc[2];
        __builtin_amdgcn_s_setprio(1);
#pragma unroll
        for (int tb = 0; tb < 2; ++tb) {
            int row = tb * 32 + q5;
            int rsw = (row & 7) << 4;
            f32x16 s = (f32x16)(-mrun);
#pragma unroll
            for (int m = 0; m < 4; ++m) {
                bf16x8 kf = *reinterpret_cast<const bf16x8*>(kls + row * 128 + ((m * 32 + hi * 16) ^ rsw));
                s = __builtin_amdgcn_mfma_f32_32x32x16_bf16(kf, qf[m], s, 0, 0, 0);
            }
            sc[tb] = s;
        }
        __builtin_amdgcn_s_setprio(0);

        // 3-ary max tree (v_max3 fusion) over this lane's 32 adjusted scores
        float tm[11];
#pragma unroll
        for (int i = 0; i < 10; ++i) {
            float a0 = (3 * i < 16)     ? sc[0][3 * i]      : sc[1][3 * i - 16];
            float a1 = (3 * i + 1 < 16) ? sc[0][3 * i + 1]  : sc[1][3 * i + 1 - 16];
            float a2 = (3 * i + 2 < 16) ? sc[0][3 * i + 2]  : sc[1][3 * i + 2 - 16];
            tm[i] = fmaxf(fmaxf(a0, a1), a2);
        }
        tm[10] = fmaxf(sc[1][14], sc[1][15]);
        float u0 = fmaxf(fmaxf(tm[0], tm[1]), tm[2]);
        float u1 = fmaxf(fmaxf(tm[3], tm[4]), tm[5]);
        float u2 = fmaxf(fmaxf(tm[6], tm[7]), tm[8]);
        float u3 = fmaxf(tm[9], tm[10]);
        float lm = fmaxf(fmaxf(fmaxf(u0, u1), u2), u3);   // = max(S) - mrun

        if (__any(lm > 8.f)) {   // rare: rescale oo, ls and shift this phase's sc
            u32x2 sw = __builtin_amdgcn_permlane32_swap(__builtin_bit_cast(unsigned, lm),
                                                        __builtin_bit_cast(unsigned, lm), false, false);
            float rowmax = fmaxf(__builtin_bit_cast(float, sw[0]), __builtin_bit_cast(float, sw[1]));
            float d = fmaxf(rowmax, 0.f);      // mrun_new = mrun + d
            float al = exp2f(-d);
            mrun += d;
#pragma unroll
            for (int r = 0; r < 16; ++r) {
                float alr = __shfl(al, (r & 3) + 8 * (r >> 2) + 4 * hi);
                oo[0][r] *= alr; oo[1][r] *= alr; ls[r] *= alr;
            }
#pragma unroll
            for (int tb = 0; tb < 2; ++tb)
#pragma unroll
                for (int r = 0; r < 16; ++r)
                    sc[tb][r] -= d;
        }

        // exp: no subtract in the common path
#pragma unroll
        for (int tb = 0; tb < 2; ++tb)
#pragma unroll
            for (int r = 0; r < 16; ++r)
                sc[tb][r] = exp2f(sc[tb][r]);

        // P -> bf16 A-frags: 16 cvt_pk + 8 permlane32_swap
        u32x4 paw[4];
#pragma unroll
        for (int tb = 0; tb < 2; ++tb)
#pragma unroll
            for (int u2i = 0; u2i < 2; ++u2i)
#pragma unroll
                for (int e = 0; e < 2; ++e) {
                    unsigned wd = cvt_pk_bf16(sc[tb][8 * u2i + 2 * e], sc[tb][8 * u2i + 2 * e + 1]);
                    unsigned ws = cvt_pk_bf16(sc[tb][8 * u2i + 4 + 2 * e], sc[tb][8 * u2i + 4 + 2 * e + 1]);
                    u32x2 rr = __builtin_amdgcn_permlane32_swap(wd, ws, false, false);
                    paw[tb * 2 + u2i][e] = rr[0];
                    paw[tb * 2 + u2i][2 + e] = rr[1];
                }

        // PV + ones-MFMA row-sums
        __builtin_amdgcn_s_setprio(1);
#pragma unroll
        for (int dblk = 0; dblk < 2; ++dblk) {
            int row = dblk * 32 + q5;
            int rsw = (row & 7) << 4;
#pragma unroll
            for (int ks = 0; ks < 4; ++ks) {
                bf16x8 vf = *reinterpret_cast<const bf16x8*>(
                    vls + row * 128 + ((ks * 32 + hi * 16) ^ rsw));
                oo[dblk] = __builtin_amdgcn_mfma_f32_32x32x16_bf16(
                    __builtin_bit_cast(bf16x8, paw[ks]), vf, oo[dblk], 0, 0, 0);
            }
        }
#pragma unroll
        for (int ks = 0; ks < 4; ++ks)
            ls = __builtin_amdgcn_mfma_f32_32x32x16_bf16(
                __builtin_bit_cast(bf16x8, paw[ks]), ones8, ls, 0, 0, 0);
        __builtin_amdgcn_s_setprio(0);
    }

    int b = bh >> 4, h = bh & 15;
#pragma unroll
    for (int r = 0; r < 16; ++r) {
        float invr = 1.f / ls[r];
        int qrel = (r & 3) + 8 * (r >> 2) + 4 * hi;
        int s = qr + qrel;
        size_t base = ((size_t)(b * SS + s)) * DMODEL + h * DHEAD;
        ctxo[base + q5]      = f2bf(oo[0][r] * invr);
        ctxo[base + 32 + q5] = f2bf(oo[1][r] * invr);
    }
}

// ---------------- output projection -> BF16 proj (halves proj/LN bandwidth) ----------------
__global__ __launch_bounds__(256, 2) void gemm_proj(
    const unsigned short* __restrict__ ctxb, const unsigned short* __restrict__ Wdb,
    const float* __restrict__ bd, unsigned short* __restrict__ projb) {
    __shared__ unsigned short Als[2][8192];   // [128 m][64 k]
    __shared__ unsigned short Bls[2][4096];   // [64 n][64 k]
    int L = blockIdx.x;
    int wg = (L & 7) * 64 + (L >> 3);         // 512 = 8*64
    int n0 = (wg & 15) * 64, m0 = (wg >> 4) * 128;

    int t = threadIdx.x, wv = t >> 6, lane = t & 63;
    int q5 = lane & 31, hi = lane >> 5;
    int wm = wv >> 1, wn = wv & 1;
    const char* Ac = (const char*)ctxb;
    const char* Bc = (const char*)Wdb;

    auto stage = [&](int bf, int k0) {
#pragma unroll
        for (int i = 0; i < 4; ++i) {
            int c = t + 256 * i;
            int kr = c >> 3, kc = ((c & 7) << 4) ^ ((kr & 7) << 4);
            gload_lds16b(Ac + ((size_t)(m0 + kr) * DMODEL + k0) * 2 + kc, (char*)&Als[bf][0] + c * 16);
        }
#pragma unroll
        for (int i = 0; i < 2; ++i) {
            int c = t + 256 * i;
            int kr = c >> 3, kc = ((c & 7) << 4) ^ ((kr & 7) << 4);
            gload_lds16b(Bc + ((size_t)(n0 + kr) * DMODEL + k0) * 2 + kc, (char*)&Bls[bf][0] + c * 16);
        }
    };

    f32x16 acc[2];
    acc[0] = (f32x16)0.f; acc[1] = (f32x16)0.f;

    stage(0, 0);
    int buf = 0;
    for (int k0 = 0; k0 < DMODEL; k0 += 64) {
        __builtin_amdgcn_s_barrier();
        if (k0 + 64 < DMODEL) {
            stage(buf ^ 1, k0 + 64);
            asm volatile("s_waitcnt vmcnt(6)" ::: "memory");
        } else {
            asm volatile("s_waitcnt vmcnt(0)" ::: "memory");
        }
        __builtin_amdgcn_sched_barrier(0);
        __builtin_amdgcn_s_barrier();
        __builtin_amdgcn_sched_barrier(0);

        const char* als = (const char*)&Als[buf][0];
        const char* bls = (const char*)&Bls[buf][0];
        __builtin_amdgcn_s_setprio(1);
#pragma unroll
        for (int ks = 0; ks < 4; ++ks) {
            int kb = ks * 32 + hi * 16;
            bf16x8 af[2], bfr;
#pragma unroll
            for (int fm = 0; fm < 2; ++fm) {
                int row = wm * 64 + fm * 32 + q5;
                af[fm] = *reinterpret_cast<const bf16x8*>(als + row * 128 + (kb ^ ((row & 7) << 4)));
            }
            {
                int row = wn * 32 + q5;
                bfr = *reinterpret_cast<const bf16x8*>(bls + row * 128 + (kb ^ ((row & 7) << 4)));
            }
#pragma unroll
            for (int fm = 0; fm < 2; ++fm)
                acc[fm] = __builtin_amdgcn_mfma_f32_32x32x16_bf16(af[fm], bfr, acc[fm], 0, 0, 0);
        }
        __builtin_amdgcn_s_setprio(0);
        buf ^= 1;
    }

    int col = n0 + wn * 32 + q5;
    float bi = bd[col];
#pragma unroll
    for (int fm = 0; fm < 2; ++fm)
#pragma unroll
        for (int r = 0; r < 16; ++r) {
            int row = m0 + wm * 64 + fm * 32 + (r & 3) + 8 * (r >> 2) + 4 * hi;
            projb[(size_t)row * DMODEL + col] = f2bf(acc[fm][r] + bi);
        }
}

// ---------------- LayerNorm over D=1024 (bf16 input) ----------------
__global__ __launch_bounds__(256) void ln_kernel(const unsigned short* __restrict__ projb,
                                                 const float* __restrict__ g,
                                                 const float* __restrict__ bv,
                                                 float* __restrict__ out) {
    int row = blockIdx.x, t = threadIdx.x;
    ushort4 u = reinterpret_cast<const ushort4*>(projb + (size_t)row * DMODEL)[t];
    float4 v;
    v.x = bf2f(u.x); v.y = bf2f(u.y); v.z = bf2f(u.z); v.w = bf2f(u.w);
    float s  = v.x + v.y + v.z + v.w;
    float s2 = v.x * v.x + v.y * v.y + v.z * v.z + v.w * v.w;
#pragma unroll
    for (int m = 1; m < 64; m <<= 1) { s += __shfl_xor(s, m); s2 += __shfl_xor(s2, m); }
    __shared__ float red[8];
    int wv = t >> 6, lane = t & 63;
    if (lane == 0) { red[wv] = s; red[wv + 4] = s2; }
    __syncthreads();
    s  = red[0] + red[1] + red[2] + red[3];
    s2 = red[4] + red[5] + red[6] + red[7];
    float mu  = s * (1.f / 1024.f);
    float var = s2 * (1.f / 1024.f) - mu * mu;
    float inv = rsqrtf(var + 1e-12f);
    float4 gv = reinterpret_cast<const float4*>(g)[t];
    float4 bb = reinterpret_cast<const float4*>(bv)[t];
    float4 ov;
    ov.x = (v.x - mu) * inv * gv.x + bb.x;
    ov.y = (v.y - mu) * inv * gv.y + bb.y;
    ov.z = (v.z - mu) * inv * gv.z + bb.z;
    ov.w = (v.w - mu) * inv * gv.w + bb.w;
    reinterpret_cast<float4*>(out + (size_t)row * DMODEL)[t] = ov;
}

extern "C" void kernel_launch(void* const* d_in, const int* in_sizes, int n_in,
                              void* d_out, int out_size, void* d_ws, size_t ws_size,
                              hipStream_t stream) {
    const float* x   = (const float*)d_in[0];
    const float* Wq  = (const float*)d_in[1];
    const float* bq  = (const float*)d_in[2];
    const float* Wk  = (const float*)d_in[3];
    const float* bk  = (const float*)d_in[4];
    const float* Wv  = (const float*)d_in[5];
    const float* bv  = (const float*)d_in[6];
    const float* Wd  = (const float*)d_in[7];
    const float* bd  = (const float*)d_in[8];
    const float* lng = (const float*)d_in[9];
    const float* lnb = (const float*)d_in[10];

    char* ws = (char*)d_ws;
    unsigned short* xb    = (unsigned short*)(ws);                    // 8 MB
    unsigned short* Wqb   = (unsigned short*)(ws + (8u  << 20));      // 2 MB each
    unsigned short* Wkb   = (unsigned short*)(ws + (10u << 20));
    unsigned short* Wvb   = (unsigned short*)(ws + (12u << 20));
    unsigned short* Wdb   = (unsigned short*)(ws + (14u << 20));
    unsigned short* Qb    = (unsigned short*)(ws + (16u << 20));      // 8 MB
    unsigned short* Kb    = (unsigned short*)(ws + (24u << 20));      // 8 MB
    unsigned short* VTb   = (unsigned short*)(ws + (32u << 20));      // 8 MB
    unsigned short* ctxb  = (unsigned short*)(ws + (40u << 20));      // 8 MB
    unsigned short* projb = (unsigned short*)(ws + (16u << 20));      // 8 MB, aliases Qb (dead after attn)

    cvt_all<<<dim3(1024, 8), 256, 0, stream>>>(x, Wq, Wk, Wv, Wd, xb, Wqb, Wkb, Wvb, Wdb);
    gemm_qkv<<<768, 256, 0, stream>>>(xb, Wqb, Wkb, Wvb, bq, bk, bv, Qb, Kb, VTb);
    attn_kernel<<<dim3(16, 32), 256, 0, stream>>>(Qb, Kb, VTb, ctxb);
    gemm_proj<<<512, 256, 0, stream>>>(ctxb, Wdb, bd, projb);
    ln_kernel<<<4096, 256, 0, stream>>>(projb, lng, lnb, (float*)d_out);
}

// Round 16
// 134.991 us; speedup vs baseline: 1.8691x; 1.0006x over previous
//
#include <hip/hip_runtime.h>

#define HD 16
#define DHEAD 64
#define DMODEL 1024
#define BB 2
#define SS 2048
#define MTOT (BB*SS)   // 4096
#define LOG2E 1.44269504f

typedef float f32x4 __attribute__((ext_vector_type(4)));
typedef float f32x16 __attribute__((ext_vector_type(16)));
typedef __bf16 bf16x8 __attribute__((ext_vector_type(8)));
typedef unsigned short u16x8 __attribute__((ext_vector_type(8)));
typedef unsigned int u32x2 __attribute__((ext_vector_type(2)));
typedef unsigned int u32x4 __attribute__((ext_vector_type(4)));

__device__ __forceinline__ unsigned short f2bf(float f) {
    unsigned int u = __builtin_bit_cast(unsigned int, f);
    unsigned int r = (u + 0x7fffu + ((u >> 16) & 1u)) >> 16;   // RNE
    return (unsigned short)r;
}

__device__ __forceinline__ float bf2f(unsigned short u) {
    return __builtin_bit_cast(float, ((unsigned int)u) << 16);
}

__device__ __forceinline__ bf16x8 ld8(const unsigned short* p) {
    u16x8 v = *reinterpret_cast<const u16x8*>(p);
    return __builtin_bit_cast(bf16x8, v);
}

__device__ __forceinline__ void gload_lds16b(const char* g, char* l) {
    __builtin_amdgcn_global_load_lds(
        (const __attribute__((address_space(1))) void*)g,
        (__attribute__((address_space(3))) void*)l, 16, 0, 0);
}

__device__ __forceinline__ unsigned cvt_pk_bf16(float lo, float hi) {
    unsigned r;
    asm("v_cvt_pk_bf16_f32 %0, %1, %2" : "=v"(r) : "v"(lo), "v"(hi));
    return r;
}

// ---------------- fp32 -> bf16 converts (one launch: 4 weights + x) ----------------
__global__ __launch_bounds__(256) void cvt_all(
    const float* __restrict__ x,
    const float* __restrict__ w0, const float* __restrict__ w1,
    const float* __restrict__ w2, const float* __restrict__ w3,
    unsigned short* __restrict__ xb,
    unsigned short* __restrict__ o0, unsigned short* __restrict__ o1,
    unsigned short* __restrict__ o2, unsigned short* __restrict__ o3) {
    int y = blockIdx.y;
    const float* in;
    unsigned short* out;
    int idx;
    if (y < 4) {
        in  = (y == 0) ? w0 : (y == 1) ? w1 : (y == 2) ? w2 : w3;
        out = (y == 0) ? o0 : (y == 1) ? o1 : (y == 2) ? o2 : o3;
        idx = blockIdx.x * 256 + threadIdx.x;
    } else {
        in  = x;
        out = xb;
        idx = ((y - 4) * 1024 + blockIdx.x) * 256 + threadIdx.x;
    }
    float4 v = reinterpret_cast<const float4*>(in)[idx];
    ushort4 o;
    o.x = f2bf(v.x); o.y = f2bf(v.y); o.z = f2bf(v.z); o.w = f2bf(v.w);
    reinterpret_cast<ushort4*>(out)[idx] = o;
}

// ---------------- QKV projection: 128x128 tile, BK=64, 32x32 MFMA, dbuf+counted vmcnt ----------------
__global__ __launch_bounds__(256, 2) void gemm_qkv(
    const unsigned short* __restrict__ xb,
    const unsigned short* __restrict__ Wqb, const unsigned short* __restrict__ Wkb,
    const unsigned short* __restrict__ Wvb,
    const float* __restrict__ bq, const float* __restrict__ bk, const float* __restrict__ bv,
    unsigned short* __restrict__ Qo, unsigned short* __restrict__ Ko, unsigned short* __restrict__ VTo) {
    __shared__ unsigned short Als[2][8192];   // [128 m][64 k] bf16, swizzled, 16KB/buf
    __shared__ unsigned short Bls[2][8192];   // [128 n][64 k]
    int L = blockIdx.x;
    int wg = (L & 7) * 96 + (L >> 3);         // bijective XCD-chunked remap (768 = 8*96)
    int z = wg >> 8, rem = wg & 255;
    int n0 = (rem & 7) * 128, m0 = (rem >> 3) * 128;
    const unsigned short* Bm = (z == 0) ? Wqb : (z == 1) ? Wkb : Wvb;
    const float* bias = (z == 0) ? bq : (z == 1) ? bk : bv;

    int t = threadIdx.x, wv = t >> 6, lane = t & 63;
    int q5 = lane & 31, hi = lane >> 5;
    int wm = wv >> 1, wn = wv & 1;
    const char* Ac = (const char*)xb;
    const char* Bc = (const char*)Bm;

    auto stage = [&](int bf, int k0) {
#pragma unroll
        for (int i = 0; i < 4; ++i) {
            int c = t + 256 * i;
            int kr = c >> 3, kc = ((c & 7) << 4) ^ ((kr & 7) << 4);
            gload_lds16b(Ac + ((size_t)(m0 + kr) * DMODEL + k0) * 2 + kc, (char*)&Als[bf][0] + c * 16);
        }
#pragma unroll
        for (int i = 0; i < 4; ++i) {
            int c = t + 256 * i;
            int kr = c >> 3, kc = ((c & 7) << 4) ^ ((kr & 7) << 4);
            gload_lds16b(Bc + ((size_t)(n0 + kr) * DMODEL + k0) * 2 + kc, (char*)&Bls[bf][0] + c * 16);
        }
    };

    f32x16 acc[2][2];
#pragma unroll
    for (int fm = 0; fm < 2; ++fm)
#pragma unroll
        for (int fn = 0; fn < 2; ++fn) acc[fm][fn] = (f32x16)0.f;

    stage(0, 0);
    int buf = 0;
    for (int k0 = 0; k0 < DMODEL; k0 += 64) {
        __builtin_amdgcn_s_barrier();
        if (k0 + 64 < DMODEL) {
            stage(buf ^ 1, k0 + 64);
            asm volatile("s_waitcnt vmcnt(8)" ::: "memory");
        } else {
            asm volatile("s_waitcnt vmcnt(0)" ::: "memory");
        }
        __builtin_amdgcn_sched_barrier(0);
        __builtin_amdgcn_s_barrier();
        __builtin_amdgcn_sched_barrier(0);

        const char* als = (const char*)&Als[buf][0];
        const char* bls = (const char*)&Bls[buf][0];
        __builtin_amdgcn_s_setprio(1);
#pragma unroll
        for (int ks = 0; ks < 4; ++ks) {
            int kb = ks * 32 + hi * 16;
            bf16x8 af[2], bfr[2];
#pragma unroll
            for (int fm = 0; fm < 2; ++fm) {
                int row = wm * 64 + fm * 32 + q5;
                af[fm] = *reinterpret_cast<const bf16x8*>(als + row * 128 + (kb ^ ((row & 7) << 4)));
            }
#pragma unroll
            for (int fn = 0; fn < 2; ++fn) {
                int row = wn * 64 + fn * 32 + q5;
                bfr[fn] = *reinterpret_cast<const bf16x8*>(bls + row * 128 + (kb ^ ((row & 7) << 4)));
            }
#pragma unroll
            for (int fm = 0; fm < 2; ++fm)
#pragma unroll
                for (int fn = 0; fn < 2; ++fn)
                    acc[fm][fn] = __builtin_amdgcn_mfma_f32_32x32x16_bf16(af[fm], bfr[fn], acc[fm][fn], 0, 0, 0);
        }
        __builtin_amdgcn_s_setprio(0);
        buf ^= 1;
    }

    float scale = (z == 0) ? (0.125f * LOG2E) : 1.0f;   // fold 1/sqrt(64)*log2(e) into Q
    int b = m0 >> 11;
#pragma unroll
    for (int fm = 0; fm < 2; ++fm) {
#pragma unroll
        for (int fn = 0; fn < 2; ++fn) {
            int col = n0 + wn * 64 + fn * 32 + q5;
            int h = col >> 6, dh = col & 63;
            float bi = bias[col];
            if (z == 2) {
#pragma unroll
                for (int rq = 0; rq < 4; ++rq) {
                    int s0 = ((m0 + wm * 64 + fm * 32 + 8 * rq + 4 * hi) & 2047);
                    ushort4 pk;
                    pk.x = f2bf(acc[fm][fn][4 * rq + 0] + bi);
                    pk.y = f2bf(acc[fm][fn][4 * rq + 1] + bi);
                    pk.z = f2bf(acc[fm][fn][4 * rq + 2] + bi);
                    pk.w = f2bf(acc[fm][fn][4 * rq + 3] + bi);
                    *reinterpret_cast<ushort4*>(&VTo[((size_t)((b * HD + h) * DHEAD + dh)) * SS + s0]) = pk;
                }
            } else {
                unsigned short* o = (z == 0) ? Qo : Ko;   // [bh][s][dh]
#pragma unroll
                for (int r = 0; r < 16; ++r) {
                    int s = (m0 + wm * 64 + fm * 32 + (r & 3) + 8 * (r >> 2) + 4 * hi) & 2047;
                    o[((size_t)((b * HD + h) * SS + s)) * DHEAD + dh] = f2bf((acc[fm][fn][r] + bi) * scale);
                }
            }
        }
    }
}

// ---------------- flash attention: ring pipeline + att[2] double-pipeline (T15) ----------------
// Invariant at iter p: scA = QK(p) - mrun (computed in iter p-1). Body:
// QK(p+1)->scB (MFMA; C-init -mrun, mrun stable since iter p-1's softmax) runs
// INDEPENDENT of softmax(scA) (VALU) -> scheduler overlaps the two pipes; PV(p)
// after. Rare defer-max rescale shifts BOTH sc buffers to keep the invariant.
__global__ __launch_bounds__(256, 2) void attn_kernel(
    const unsigned short* __restrict__ Qb, const unsigned short* __restrict__ Kb,
    const unsigned short* __restrict__ VTb, unsigned short* __restrict__ ctxo) {
    __shared__ char smem[4][16384];   // ring buffers: [K 8KB | V 8KB] each
    int L = blockIdx.x + (int)gridDim.x * blockIdx.y;   // 0..511
    int wg = (L & 7) * 64 + (L >> 3);                   // bijective XCD-chunked remap
    int q0 = (wg & 15) * 128;
    int bh = wg >> 4;
    int t = threadIdx.x, wv = t >> 6, lane = t & 63;
    int q5 = lane & 31, hi = lane >> 5;
    const unsigned short* Qh  = Qb  + (size_t)bh * SS * DHEAD;
    const char* Khc  = (const char*)(Kb  + (size_t)bh * SS * DHEAD);
    const char* VThc = (const char*)(VTb + (size_t)bh * DHEAD * SS);
    int qr = q0 + wv * 32;

    bf16x8 qf[4];
#pragma unroll
    for (int m = 0; m < 4; ++m)
        qf[m] = ld8(&Qh[(size_t)(qr + q5) * DHEAD + m * 16 + hi * 8]);

    const __bf16 one_bf = (__bf16)1.0f;
    bf16x8 ones8 = {one_bf, one_bf, one_bf, one_bf, one_bf, one_bf, one_bf, one_bf};

    f32x16 oo[2];
    oo[0] = (f32x16)0.f; oo[1] = (f32x16)0.f;
    f32x16 ls = (f32x16)0.f;   // row-sums (o-layout) via mfma(P, ones)
    float mrun = 0.f;          // log2-units, lane-scalar (q=q5); defer-max THR=8

    auto stage = [&](int ph) {
        char* kb = smem[ph & 3];
        char* vb = kb + 8192;
        int t0 = ph * 64;
#pragma unroll
        for (int i = 0; i < 2; ++i) {
            int c = t + 256 * i;
            int kr = c >> 3, kc = ((c & 7) << 4) ^ ((kr & 7) << 4);
            gload_lds16b(Khc + (size_t)(t0 + kr) * 128 + kc, kb + c * 16);
        }
#pragma unroll
        for (int i = 0; i < 2; ++i) {
            int c = t + 256 * i;
            int vr = c >> 3, vc = ((c & 7) << 4) ^ ((vr & 7) << 4);
            gload_lds16b(VThc + ((size_t)vr * SS + t0) * 2 + vc, vb + c * 16);
        }
    };

    // QK^T of phase php into scn; C initialized to -mrun so scn = S - mrun
    auto qk_into = [&](int php, f32x16 (&scn)[2]) {
        const char* kls = smem[php & 3];
        __builtin_amdgcn_s_setprio(1);
#pragma unroll
        for (int tb = 0; tb < 2; ++tb) {
            int row = tb * 32 + q5;
            int rsw = (row & 7) << 4;
            f32x16 s = (f32x16)(-mrun);
#pragma unroll
            for (int m = 0; m < 4; ++m) {
                bf16x8 kf = *reinterpret_cast<const bf16x8*>(kls + row * 128 + ((m * 32 + hi * 16) ^ rsw));
                s = __builtin_amdgcn_mfma_f32_32x32x16_bf16(kf, qf[m], s, 0, 0, 0);
            }
            scn[tb] = s;
        }
        __builtin_amdgcn_s_setprio(0);
    };

    f32x16 scA[2], scB[2];

    stage(0); stage(1); stage(2);   // 12 loads in flight
    asm volatile("s_waitcnt vmcnt(8)" ::: "memory");   // stage(0) complete
    __builtin_amdgcn_sched_barrier(0);
    __builtin_amdgcn_s_barrier();
    __builtin_amdgcn_sched_barrier(0);
    qk_into(0, scA);

    auto body = [&](int ph, f32x16 (&scc)[2], f32x16 (&scn)[2]) {
        // guarantee stage(ph+1) landed (QK(ph+1) reads it); keep later stages in flight
        if (ph < 30) asm volatile("s_waitcnt vmcnt(4)" ::: "memory");
        else         asm volatile("s_waitcnt vmcnt(0)" ::: "memory");
        __builtin_amdgcn_sched_barrier(0);
        __builtin_amdgcn_s_barrier();
        __builtin_amdgcn_sched_barrier(0);

        if (ph + 3 < 32) stage(ph + 3);      // slot (ph-1)&3, barrier-protected
        if (ph + 1 < 32) qk_into(ph + 1, scn);   // MFMA: independent of softmax(scc)

        // softmax on scc = S(ph) - mrun (VALU; overlaps QK(ph+1) MFMAs)
        float tm[11];
#pragma unroll
        for (int i = 0; i < 10; ++i) {
            float a0 = (3 * i < 16)     ? scc[0][3 * i]      : scc[1][3 * i - 16];
            float a1 = (3 * i + 1 < 16) ? scc[0][3 * i + 1]  : scc[1][3 * i + 1 - 16];
            float a2 = (3 * i + 2 < 16) ? scc[0][3 * i + 2]  : scc[1][3 * i + 2 - 16];
            tm[i] = fmaxf(fmaxf(a0, a1), a2);
        }
        tm[10] = fmaxf(scc[1][14], scc[1][15]);
        float u0 = fmaxf(fmaxf(tm[0], tm[1]), tm[2]);
        float u1 = fmaxf(fmaxf(tm[3], tm[4]), tm[5]);
        float u2 = fmaxf(fmaxf(tm[6], tm[7]), tm[8]);
        float u3 = fmaxf(tm[9], tm[10]);
        float lm = fmaxf(fmaxf(fmaxf(u0, u1), u2), u3);   // = max(S) - mrun

        if (__any(lm > 8.f)) {   // rare: rescale oo/ls, shift BOTH sc buffers, bump mrun
            u32x2 sw = __builtin_amdgcn_permlane32_swap(__builtin_bit_cast(unsigned, lm),
                                                        __builtin_bit_cast(unsigned, lm), false, false);
            float rowmax = fmaxf(__builtin_bit_cast(float, sw[0]), __builtin_bit_cast(float, sw[1]));
            float d = fmaxf(rowmax, 0.f);      // mrun_new = mrun + d
            float al = exp2f(-d);
            mrun += d;
#pragma unroll
            for (int r = 0; r < 16; ++r) {
                float alr = __shfl(al, (r & 3) + 8 * (r >> 2) + 4 * hi);
                oo[0][r] *= alr; oo[1][r] *= alr; ls[r] *= alr;
            }
#pragma unroll
            for (int tb = 0; tb < 2; ++tb)
#pragma unroll
                for (int r = 0; r < 16; ++r) {
                    scc[tb][r] -= d;
                    scn[tb][r] -= d;          // keep scn = S(ph+1) - mrun invariant
                }
        }

        // exp: no subtract in the common path
#pragma unroll
        for (int tb = 0; tb < 2; ++tb)
#pragma unroll
            for (int r = 0; r < 16; ++r)
                scc[tb][r] = exp2f(scc[tb][r]);

        // P -> bf16 A-frags: 16 cvt_pk + 8 permlane32_swap
        u32x4 paw[4];
#pragma unroll
        for (int tb = 0; tb < 2; ++tb)
#pragma unroll
            for (int u2i = 0; u2i < 2; ++u2i)
#pragma unroll
                for (int e = 0; e < 2; ++e) {
                    unsigned wd = cvt_pk_bf16(scc[tb][8 * u2i + 2 * e], scc[tb][8 * u2i + 2 * e + 1]);
                    unsigned ws = cvt_pk_bf16(scc[tb][8 * u2i + 4 + 2 * e], scc[tb][8 * u2i + 4 + 2 * e + 1]);
                    u32x2 rr = __builtin_amdgcn_permlane32_swap(wd, ws, false, false);
                    paw[tb * 2 + u2i][e] = rr[0];
                    paw[tb * 2 + u2i][2 + e] = rr[1];
                }

        // PV + ones-MFMA row-sums (V of phase ph)
        const char* vls = smem[ph & 3] + 8192;
        __builtin_amdgcn_s_setprio(1);
#pragma unroll
        for (int dblk = 0; dblk < 2; ++dblk) {
            int row = dblk * 32 + q5;
            int rsw = (row & 7) << 4;
#pragma unroll
            for (int ks = 0; ks < 4; ++ks) {
                bf16x8 vf = *reinterpret_cast<const bf16x8*>(
                    vls + row * 128 + ((ks * 32 + hi * 16) ^ rsw));
                oo[dblk] = __builtin_amdgcn_mfma_f32_32x32x16_bf16(
                    __builtin_bit_cast(bf16x8, paw[ks]), vf, oo[dblk], 0, 0, 0);
            }
        }
#pragma unroll
        for (int ks = 0; ks < 4; ++ks)
            ls = __builtin_amdgcn_mfma_f32_32x32x16_bf16(
                __builtin_bit_cast(bf16x8, paw[ks]), ones8, ls, 0, 0, 0);
        __builtin_amdgcn_s_setprio(0);
    };

    for (int pp = 0; pp < 16; ++pp) {
        body(2 * pp,     scA, scB);
        body(2 * pp + 1, scB, scA);
    }

    int b = bh >> 4, h = bh & 15;
#pragma unroll
    for (int r = 0; r < 16; ++r) {
        float invr = 1.f / ls[r];
        int qrel = (r & 3) + 8 * (r >> 2) + 4 * hi;
        int s = qr + qrel;
        size_t base = ((size_t)(b * SS + s)) * DMODEL + h * DHEAD;
        ctxo[base + q5]      = f2bf(oo[0][r] * invr);
        ctxo[base + 32 + q5] = f2bf(oo[1][r] * invr);
    }
}

// ---------------- output projection -> BF16 proj (halves proj/LN bandwidth) ----------------
__global__ __launch_bounds__(256, 2) void gemm_proj(
    const unsigned short* __restrict__ ctxb, const unsigned short* __restrict__ Wdb,
    const float* __restrict__ bd, unsigned short* __restrict__ projb) {
    __shared__ unsigned short Als[2][8192];   // [128 m][64 k]
    __shared__ unsigned short Bls[2][4096];   // [64 n][64 k]
    int L = blockIdx.x;
    int wg = (L & 7) * 64 + (L >> 3);         // 512 = 8*64
    int n0 = (wg & 15) * 64, m0 = (wg >> 4) * 128;

    int t = threadIdx.x, wv = t >> 6, lane = t & 63;
    int q5 = lane & 31, hi = lane >> 5;
    int wm = wv >> 1, wn = wv & 1;
    const char* Ac = (const char*)ctxb;
    const char* Bc = (const char*)Wdb;

    auto stage = [&](int bf, int k0) {
#pragma unroll
        for (int i = 0; i < 4; ++i) {
            int c = t + 256 * i;
            int kr = c >> 3, kc = ((c & 7) << 4) ^ ((kr & 7) << 4);
            gload_lds16b(Ac + ((size_t)(m0 + kr) * DMODEL + k0) * 2 + kc, (char*)&Als[bf][0] + c * 16);
        }
#pragma unroll
        for (int i = 0; i < 2; ++i) {
            int c = t + 256 * i;
            int kr = c >> 3, kc = ((c & 7) << 4) ^ ((kr & 7) << 4);
            gload_lds16b(Bc + ((size_t)(n0 + kr) * DMODEL + k0) * 2 + kc, (char*)&Bls[bf][0] + c * 16);
        }
    };

    f32x16 acc[2];
    acc[0] = (f32x16)0.f; acc[1] = (f32x16)0.f;

    stage(0, 0);
    int buf = 0;
    for (int k0 = 0; k0 < DMODEL; k0 += 64) {
        __builtin_amdgcn_s_barrier();
        if (k0 + 64 < DMODEL) {
            stage(buf ^ 1, k0 + 64);
            asm volatile("s_waitcnt vmcnt(6)" ::: "memory");
        } else {
            asm volatile("s_waitcnt vmcnt(0)" ::: "memory");
        }
        __builtin_amdgcn_sched_barrier(0);
        __builtin_amdgcn_s_barrier();
        __builtin_amdgcn_sched_barrier(0);

        const char* als = (const char*)&Als[buf][0];
        const char* bls = (const char*)&Bls[buf][0];
        __builtin_amdgcn_s_setprio(1);
#pragma unroll
        for (int ks = 0; ks < 4; ++ks) {
            int kb = ks * 32 + hi * 16;
            bf16x8 af[2], bfr;
#pragma unroll
            for (int fm = 0; fm < 2; ++fm) {
                int row = wm * 64 + fm * 32 + q5;
                af[fm] = *reinterpret_cast<const bf16x8*>(als + row * 128 + (kb ^ ((row & 7) << 4)));
            }
            {
                int row = wn * 32 + q5;
                bfr = *reinterpret_cast<const bf16x8*>(bls + row * 128 + (kb ^ ((row & 7) << 4)));
            }
#pragma unroll
            for (int fm = 0; fm < 2; ++fm)
                acc[fm] = __builtin_amdgcn_mfma_f32_32x32x16_bf16(af[fm], bfr, acc[fm], 0, 0, 0);
        }
        __builtin_amdgcn_s_setprio(0);
        buf ^= 1;
    }

    int col = n0 + wn * 32 + q5;
    float bi = bd[col];
#pragma unroll
    for (int fm = 0; fm < 2; ++fm)
#pragma unroll
        for (int r = 0; r < 16; ++r) {
            int row = m0 + wm * 64 + fm * 32 + (r & 3) + 8 * (r >> 2) + 4 * hi;
            projb[(size_t)row * DMODEL + col] = f2bf(acc[fm][r] + bi);
        }
}

// ---------------- LayerNorm over D=1024 (bf16 input) ----------------
__global__ __launch_bounds__(256) void ln_kernel(const unsigned short* __restrict__ projb,
                                                 const float* __restrict__ g,
                                                 const float* __restrict__ bv,
                                                 float* __restrict__ out) {
    int row = blockIdx.x, t = threadIdx.x;
    ushort4 u = reinterpret_cast<const ushort4*>(projb + (size_t)row * DMODEL)[t];
    float4 v;
    v.x = bf2f(u.x); v.y = bf2f(u.y); v.z = bf2f(u.z); v.w = bf2f(u.w);
    float s  = v.x + v.y + v.z + v.w;
    float s2 = v.x * v.x + v.y * v.y + v.z * v.z + v.w * v.w;
#pragma unroll
    for (int m = 1; m < 64; m <<= 1) { s += __shfl_xor(s, m); s2 += __shfl_xor(s2, m); }
    __shared__ float red[8];
    int wv = t >> 6, lane = t & 63;
    if (lane == 0) { red[wv] = s; red[wv + 4] = s2; }
    __syncthreads();
    s  = red[0] + red[1] + red[2] + red[3];
    s2 = red[4] + red[5] + red[6] + red[7];
    float mu  = s * (1.f / 1024.f);
    float var = s2 * (1.f / 1024.f) - mu * mu;
    float inv = rsqrtf(var + 1e-12f);
    float4 gv = reinterpret_cast<const float4*>(g)[t];
    float4 bb = reinterpret_cast<const float4*>(bv)[t];
    float4 ov;
    ov.x = (v.x - mu) * inv * gv.x + bb.x;
    ov.y = (v.y - mu) * inv * gv.y + bb.y;
    ov.z = (v.z - mu) * inv * gv.z + bb.z;
    ov.w = (v.w - mu) * inv * gv.w + bb.w;
    reinterpret_cast<float4*>(out + (size_t)row * DMODEL)[t] = ov;
}

extern "C" void kernel_launch(void* const* d_in, const int* in_sizes, int n_in,
                              void* d_out, int out_size, void* d_ws, size_t ws_size,
                              hipStream_t stream) {
    const float* x   = (const float*)d_in[0];
    const float* Wq  = (const float*)d_in[1];
    const float* bq  = (const float*)d_in[2];
    const float* Wk  = (const float*)d_in[3];
    const float* bk  = (const float*)d_in[4];
    const float* Wv  = (const float*)d_in[5];
    const float* bv  = (const float*)d_in[6];
    const float* Wd  = (const float*)d_in[7];
    const float* bd  = (const float*)d_in[8];
    const float* lng = (const float*)d_in[9];
    const float* lnb = (const float*)d_in[10];

    char* ws = (char*)d_ws;
    unsigned short* xb    = (unsigned short*)(ws);                    // 8 MB
    unsigned short* Wqb   = (unsigned short*)(ws + (8u  << 20));      // 2 MB each
    unsigned short* Wkb   = (unsigned short*)(ws + (10u << 20));
    unsigned short* Wvb   = (unsigned short*)(ws + (12u << 20));
    unsigned short* Wdb   = (unsigned short*)(ws + (14u << 20));
    unsigned short* Qb    = (unsigned short*)(ws + (16u << 20));      // 8 MB
    unsigned short* Kb    = (unsigned short*)(ws + (24u << 20));      // 8 MB
    unsigned short* VTb   = (unsigned short*)(ws + (32u << 20));      // 8 MB
    unsigned short* ctxb  = (unsigned short*)(ws + (40u << 20));      // 8 MB
    unsigned short* projb = (unsigned short*)(ws + (16u << 20));      // 8 MB, aliases Qb (dead after attn)

    cvt_all<<<dim3(1024, 8), 256, 0, stream>>>(x, Wq, Wk, Wv, Wd, xb, Wqb, Wkb, Wvb, Wdb);
    gemm_qkv<<<768, 256, 0, stream>>>(xb, Wqb, Wkb, Wvb, bq, bk, bv, Qb, Kb, VTb);
    attn_kernel<<<dim3(16, 32), 256, 0, stream>>>(Qb, Kb, VTb, ctxb);
    gemm_proj<<<512, 256, 0, stream>>>(ctxb, Wdb, bd, projb);
    ln_kernel<<<4096, 256, 0, stream>>>(projb, lng, lnb, (float*)d_out);
}